// Round 7
// baseline (122.585 us; speedup 1.0000x reference)
//
#include <hip/hip_runtime.h>
#include <hip/hip_cooperative_groups.h>

namespace cg = cooperative_groups;
typedef unsigned long long ull;

// Problem constants (from reference)
#define N_BUSES     2000
#define BATCH       32
#define EDGES_PER_B 6000
#define TOTAL_BUSES (BATCH * N_BUSES)     // 64000
#define TOTAL_EDGES (BATCH * EDGES_PER_B) // 192000

#define SPLIT   8                         // blocks per image (bus-range partition)
#define BUS_PER (N_BUSES / SPLIT)         // 250 buses per block
#define TPB     1024
#define NBLOCKS (BATCH * SPLIT)           // 256 = 1 block/CU, co-resident (cooperative)
#define EPT     6                         // 6 consecutive edges per thread (tid < 1000)

// Per-block LDS hash: slot = ((key+1) << 13) | local_edge_id, 0 = empty.
// key = i*N_BUSES + j < 4e6 < 2^22; local edge id < 6000 < 2^13.
// ~750 keys/block in 2048 slots => load ~0.37.
#define HBITS 11
#define HSIZE (1 << HBITS)
#define HMASK (HSIZE - 1)

__device__ __forceinline__ unsigned hash_key(int key) {
    return ((unsigned)key * 2654435761u) >> (32 - HBITS);
}

__global__ __launch_bounds__(TPB, 4)
void fused_all(const float* __restrict__ x, const float* __restrict__ ea,
               const int* __restrict__ ei, const float* __restrict__ outputs,
               const float* __restrict__ labels, double* __restrict__ part,
               float* __restrict__ out, int out_size) {
    __shared__ ull slots[HSIZE];           // 16 KB
    __shared__ float yv_sh[2 * BUS_PER];   // 2 KB
    __shared__ double red[5][TPB / 64];
    __shared__ double red2[3][TPB / 64];
    __shared__ float bst[3];
    __shared__ int pend[64];
    __shared__ int npend;

    const int blk = blockIdx.x;
    const int b = blk / SPLIT;             // image
    const int p = blk % SPLIT;             // bus-range part
    const int r0 = p * BUS_PER;
    const int tid = threadIdx.x;
    const int wave = tid >> 6, lane = tid & 63;

    // ---- Prefetch A: phase-2 operands (independent; in flight through the
    // whole edge phase) ----
    float2 q0, q1, q2, vP, lP;
    const int idxP = b * N_BUSES + r0 + tid;   // valid when tid < BUS_PER
    if (tid < BUS_PER) {
        const float2* row2 = (const float2*)(x + (size_t)idxP * 6);
        q0 = row2[0]; q1 = row2[1]; q2 = row2[2];
        vP = ((const float2*)outputs)[idxP];
        lP = ((const float2*)labels)[idxP];
    }

    // ---- Prefetch B: 6 consecutive edges per thread (tid<1000 covers 6000),
    // endpoints via 3x int2 per row (8B-aligned at 24B stride), then ea / V[j]
    // for in-range edges (independent of the hash) ----
    const bool act = tid < (EDGES_PER_B / EPT);
    int iv[EPT], jv[EPT];
    if (act) {
        const int* pi = ei + (size_t)b * EDGES_PER_B + tid * EPT;
        int2 a0 = *(const int2*)pi, a1 = *(const int2*)(pi + 2), a2 = *(const int2*)(pi + 4);
        const int* pj = pi + TOTAL_EDGES;
        int2 c0 = *(const int2*)pj, c1 = *(const int2*)(pj + 2), c2 = *(const int2*)(pj + 4);
        iv[0] = a0.x % N_BUSES; iv[1] = a0.y % N_BUSES; iv[2] = a1.x % N_BUSES;
        iv[3] = a1.y % N_BUSES; iv[4] = a2.x % N_BUSES; iv[5] = a2.y % N_BUSES;
        jv[0] = c0.x % N_BUSES; jv[1] = c0.y % N_BUSES; jv[2] = c1.x % N_BUSES;
        jv[3] = c1.y % N_BUSES; jv[4] = c2.x % N_BUSES; jv[5] = c2.y % N_BUSES;
    }
    float2 av[EPT], vv[EPT];
    bool inr[EPT];
#pragma unroll
    for (int k = 0; k < EPT; k++) {
        inr[k] = act && (iv[k] >= r0) && (iv[k] < r0 + BUS_PER);
        if (inr[k]) {
            av[k] = ((const float2*)ea)[b * EDGES_PER_B + tid * EPT + k];
            vv[k] = ((const float2*)outputs)[b * N_BUSES + jv[k]];
        }
    }

    // ---- Phase 0: zero LDS ----
    slots[tid] = 0ULL;
    slots[tid + TPB] = 0ULL;               // HSIZE == 2*TPB
    if (tid < 2 * BUS_PER) yv_sh[tid] = 0.0f;
    if (tid == 0) npend = 0;
    __syncthreads();

    // ---- Phase 1: single-pass dedup insert + compensated YV accumulation.
    // numpy fancy-assign: last write per (i,j) wins = max local edge id.
    // Duplicates share i => same block. Deposing a previous winner subtracts
    // its contribution (same key => same j => same V[j]).
#pragma unroll
    for (int k = 0; k < EPT; k++) {
        if (!inr[k]) continue;
        int e = tid * EPT + k;
        int i = iv[k], j = jv[k];
        int key = i * N_BUSES + j;
        ull tag = (ull)(unsigned)(key + 1) << 13;
        ull packed = tag | (unsigned)e;
        unsigned h = hash_key(key);
        int deposed = -1;
        bool we_add = false;
        while (true) {
            ull old = atomicCAS(&slots[h], 0ULL, packed);
            if (old == 0ULL) { we_add = true; break; }
            if ((old >> 13) == (ull)(unsigned)(key + 1)) {
                ull prev = atomicMax(&slots[h], packed);
                if (prev < packed) { we_add = true; deposed = (int)(prev & 0x1FFFULL); }
                break;
            }
            h = (h + 1) & HMASK;
        }
        if (we_add) {
            float2 a = av[k], v = vv[k];
            float addr = a.x * v.x - a.y * v.y;
            float addi = a.x * v.y + a.y * v.x;
            if (deposed >= 0) {   // rare (~5 per image): undo deposed winner
                float2 ap = ((const float2*)ea)[b * EDGES_PER_B + deposed];
                addr -= ap.x * v.x - ap.y * v.y;
                addi -= ap.x * v.y + ap.y * v.x;
            }
            int il = i - r0;
            atomicAdd(&yv_sh[2 * il],     addr);
            atomicAdd(&yv_sh[2 * il + 1], addi);
        }
    }
    __syncthreads();

    // ---- Phase 2: per-bus loss terms over our 250-bus range ----
    double t0 = 0.0, t1 = 0.0, t2 = 0.0, t3 = 0.0, t4 = 0.0;
    if (tid < BUS_PER) {
        int il = tid;
        float sre = q0.x, sim = q0.y, Vm = q1.x;
        float bt0 = q1.y, bt1 = q2.x, bt2 = q2.y;
        if ((sre == 0.0f && sim == 0.0f) || Vm == 0.0f) {
            // exact-zero fallback needs image means — defer (rare/never)
            int pp = atomicAdd(&npend, 1);
            if (pp < 64) pend[pp] = il;
        } else {
            float yvr = yv_sh[2 * il], yvi = yv_sh[2 * il + 1];
            float spr = vP.x * yvr + vP.y * yvi;   // Spred = V * conj(YV)
            float spi = vP.y * yvr - vP.x * yvi;
            float den = sre * sre + sim * sim;
            float ir = sre / den, ii = -sim / den;
            float sinv_norm = sqrtf(ir * ir + ii * ii);
            float cr = spr - sre, ci = spi - sim;
            t0 = (double)(sinv_norm * ((cr * cr - ci * ci) * bt0 + (cr * cr) * bt1));
            t1 = (double)(sinv_norm * (2.0f * cr * ci * bt0));
            float vminv = 1.0f / Vm;
            float vmag = sqrtf(vP.x * vP.x + vP.y * vP.y);
            t2 = (double)(fabsf(vmag * (bt1 + bt2) - Vm) * vminv);
            t3 = (double)(fabsf(vP.y * bt2) * vminv);
            float e0 = vP.x - lP.x, e1 = vP.y - lP.y;
            t4 = (double)(e0 * e0 + e1 * e1);
        }
    }
    for (int off = 32; off > 0; off >>= 1) {
        t0 += __shfl_down(t0, off, 64);
        t1 += __shfl_down(t1, off, 64);
        t2 += __shfl_down(t2, off, 64);
        t3 += __shfl_down(t3, off, 64);
        t4 += __shfl_down(t4, off, 64);
    }
    if (lane == 0) {
        red[0][wave] = t0; red[1][wave] = t1; red[2][wave] = t2;
        red[3][wave] = t3; red[4][wave] = t4;
    }
    __syncthreads();

    double a0 = 0, a1 = 0, a2 = 0, a3 = 0, a4 = 0;
    if (tid == 0) {
        for (int w = 0; w < TPB / 64; w++) {
            a0 += red[0][w]; a1 += red[1][w]; a2 += red[2][w];
            a3 += red[3][w]; a4 += red[4][w];
        }
    }

    // ---- Rare path: exact-zero S or Vm -> compute image means (bit-faithful)
    // and process pending buses serially. npend is uniform post-barrier.
    if (npend > 0) {
        double sre = 0.0, sim = 0.0, svm = 0.0;
        for (int i = tid; i < N_BUSES; i += TPB) {
            const float* row = x + (size_t)(b * N_BUSES + i) * 6;
            sre += (double)row[0];
            sim += (double)row[1];
            svm += (double)row[2];
        }
        for (int off = 32; off > 0; off >>= 1) {
            sre += __shfl_down(sre, off, 64);
            sim += __shfl_down(sim, off, 64);
            svm += __shfl_down(svm, off, 64);
        }
        if (lane == 0) { red2[0][wave] = sre; red2[1][wave] = sim; red2[2][wave] = svm; }
        __syncthreads();
        if (tid == 0) {
            double sa = 0, sb = 0, sc = 0;
            for (int w = 0; w < TPB / 64; w++) { sa += red2[0][w]; sb += red2[1][w]; sc += red2[2][w]; }
            bst[0] = (float)(sa / N_BUSES);
            bst[1] = (float)(sb / N_BUSES);
            bst[2] = (float)(sc / N_BUSES);
        }
        __syncthreads();
        if (tid == 0) {
            int np = npend < 64 ? npend : 64;
            for (int q = 0; q < np; q++) {
                int il = pend[q];
                int idx = b * N_BUSES + r0 + il;
                const float2* row2 = (const float2*)(x + (size_t)idx * 6);
                float2 w0 = row2[0], w1 = row2[1], w2 = row2[2];
                float sr = w0.x, si = w0.y, Vm = w1.x;
                float bt0 = w1.y, bt1 = w2.x, bt2 = w2.y;
                float2 v = ((const float2*)outputs)[idx];
                float yvr = yv_sh[2 * il], yvi = yv_sh[2 * il + 1];
                float spr = v.x * yvr + v.y * yvi;
                float spi = v.y * yvr - v.x * yvi;
                float ir, ii;
                if (sr != 0.0f || si != 0.0f) {
                    float den = sr * sr + si * si;
                    ir = sr / den; ii = -si / den;
                } else {
                    float mr = bst[0], mi = bst[1];
                    float den = mr * mr + mi * mi;
                    ir = mr / den; ii = -mi / den;
                }
                float sinv_norm = sqrtf(ir * ir + ii * ii);
                float cr = spr - sr, ci = spi - si;
                a0 += (double)(sinv_norm * ((cr * cr - ci * ci) * bt0 + (cr * cr) * bt1));
                a1 += (double)(sinv_norm * (2.0f * cr * ci * bt0));
                float vminv = (Vm != 0.0f) ? (1.0f / Vm) : (1.0f / bst[2]);
                float vmag = sqrtf(v.x * v.x + v.y * v.y);
                a2 += (double)(fabsf(vmag * (bt1 + bt2) - Vm) * vminv);
                a3 += (double)(fabsf(v.y * bt2) * vminv);
                float2 l = ((const float2*)labels)[idx];
                float e0 = v.x - l.x, e1 = v.y - l.y;
                a4 += (double)(e0 * e0 + e1 * e1);
            }
        }
    }

    // ---- Publish partials at the coherence point (atomics are device-scope;
    // immune to cross-XCD L2 staleness), then grid-wide barrier ----
    if (tid == 0) {
        atomicExch((ull*)&part[blk * 5 + 0], __double_as_longlong(a0));
        atomicExch((ull*)&part[blk * 5 + 1], __double_as_longlong(a1));
        atomicExch((ull*)&part[blk * 5 + 2], __double_as_longlong(a2));
        atomicExch((ull*)&part[blk * 5 + 3], __double_as_longlong(a3));
        atomicExch((ull*)&part[blk * 5 + 4], __double_as_longlong(a4));
    }
    cg::this_grid().sync();

    // ---- Final reduction: block 0 only ----
    if (blk != 0) return;
    double v0 = 0, v1 = 0, v2 = 0, v3 = 0, v4 = 0;
    if (tid < NBLOCKS) {
        v0 = atomicAdd(&part[tid * 5 + 0], 0.0);   // coherent read
        v1 = atomicAdd(&part[tid * 5 + 1], 0.0);
        v2 = atomicAdd(&part[tid * 5 + 2], 0.0);
        v3 = atomicAdd(&part[tid * 5 + 3], 0.0);
        v4 = atomicAdd(&part[tid * 5 + 4], 0.0);
    }
    for (int off = 32; off > 0; off >>= 1) {
        v0 += __shfl_down(v0, off, 64);
        v1 += __shfl_down(v1, off, 64);
        v2 += __shfl_down(v2, off, 64);
        v3 += __shfl_down(v3, off, 64);
        v4 += __shfl_down(v4, off, 64);
    }
    __syncthreads();   // red[] reuse
    if (lane == 0 && tid < NBLOCKS) {
        red[0][wave] = v0; red[1][wave] = v1; red[2][wave] = v2;
        red[3][wave] = v3; red[4][wave] = v4;
    }
    __syncthreads();
    if (tid == 0) {
        double s0 = 0, s1 = 0, s2 = 0, s3 = 0, s4 = 0;
        for (int w = 0; w < NBLOCKS / 64; w++) {
            s0 += red[0][w]; s1 += red[1][w]; s2 += red[2][w];
            s3 += red[3][w]; s4 += red[4][w];
        }
        double inv = 1.0 / (double)TOTAL_BUSES;
        double d1re = s0 * inv, d1im = s1 * inv;
        double d2 = s2 * inv, d3 = s3 * inv;
        double mse = s4 / (2.0 * (double)TOTAL_BUSES);
        double phre = d1re + d2 + d3, phim = d1im;
        double lre = mse + 0.1 * phre, lim = 0.1 * phim;
        if (out_size == 8) {
            out[0] = (float)lre;  out[1] = (float)lim;
            out[2] = (float)phre; out[3] = (float)phim;
            out[4] = (float)d1re; out[5] = (float)d1im;
            out[6] = (float)d2;   out[7] = (float)d3;
        } else {
            float vals[5] = {(float)lre, (float)phre, (float)d1re, (float)d2, (float)d3};
            int n = out_size < 5 ? out_size : 5;
            for (int k = 0; k < n; k++) out[k] = vals[k];
            for (int k = 5; k < out_size && k < 64; k++) out[k] = 0.0f;
        }
    }
}

extern "C" void kernel_launch(void* const* d_in, const int* in_sizes, int n_in,
                              void* d_out, int out_size, void* d_ws, size_t ws_size,
                              hipStream_t stream) {
    const float* x       = (const float*)d_in[0];
    const float* ea      = (const float*)d_in[1];
    const int*   ei      = (const int*)d_in[2];
    const float* outputs = (const float*)d_in[3];
    const float* labels  = (const float*)d_in[4];
    double* part = (double*)d_ws;   // NBLOCKS * 5 doubles = 10 KB
    float* outp = (float*)d_out;

    void* args[] = {(void*)&x, (void*)&ea, (void*)&ei, (void*)&outputs,
                    (void*)&labels, (void*)&part, (void*)&outp, (void*)&out_size};
    hipLaunchCooperativeKernel((const void*)fused_all, dim3(NBLOCKS), dim3(TPB),
                               args, 0, stream);
}

// Round 8
// 86.892 us; speedup vs baseline: 1.4108x; 1.4108x over previous
//
#include <hip/hip_runtime.h>

typedef unsigned long long ull;

// Problem constants (from reference)
#define N_BUSES     2000
#define BATCH       32
#define EDGES_PER_B 6000
#define TOTAL_BUSES (BATCH * N_BUSES)     // 64000
#define TOTAL_EDGES (BATCH * EDGES_PER_B) // 192000

#define SPLIT   8                         // blocks per image (bus-range partition)
#define BUS_PER (N_BUSES / SPLIT)         // 250 buses per block
#define TPB     1024
#define NBLOCKS (BATCH * SPLIT)           // 256 (fully co-resident: 16 waves/CU)
#define EPT     6                         // 6 consecutive edges per thread (tid < 1000)

// Per-block LDS hash: slot = ((key+1) << 13) | local_edge_id, 0 = empty.
// key = i*N_BUSES + j < 4e6 < 2^22; local edge id < 6000 < 2^13.
// ~750 keys/block in 2048 slots => load ~0.37.
#define HBITS 11
#define HSIZE (1 << HBITS)
#define HMASK (HSIZE - 1)

// Workspace layout: [0,4) ticket (memset to 0 pre-launch); [64, 64+10240) partials.
#define OFF_PART 64

__device__ __forceinline__ unsigned hash_key(int key) {
    return ((unsigned)key * 2654435761u) >> (32 - HBITS);
}

__global__ __launch_bounds__(TPB)
void fused_split(const float* __restrict__ x, const float* __restrict__ ea,
                 const int* __restrict__ ei, const float* __restrict__ outputs,
                 const float* __restrict__ labels, double* __restrict__ part,
                 unsigned* __restrict__ ticket, float* __restrict__ out, int out_size) {
    __shared__ ull slots[HSIZE];           // 16 KB
    __shared__ float yv_sh[2 * BUS_PER];   // 2 KB
    __shared__ double red[5][TPB / 64];
    __shared__ double red2[3][TPB / 64];
    __shared__ float bst[3];
    __shared__ int pend[64];
    __shared__ int npend;
    __shared__ int amLast;

    const int blk = blockIdx.x;
    const int b = blk / SPLIT;             // image
    const int p = blk % SPLIT;             // bus-range part
    const int r0 = p * BUS_PER;
    const int tid = threadIdx.x;
    const int wave = tid >> 6, lane = tid & 63;

    // ---- Prefetch A: phase-2 operands (independent; in flight through the
    // whole edge phase) ----
    float2 q0, q1, q2, vP, lP;
    const int idxP = b * N_BUSES + r0 + tid;   // valid when tid < BUS_PER
    if (tid < BUS_PER) {
        const float2* row2 = (const float2*)(x + (size_t)idxP * 6);
        q0 = row2[0]; q1 = row2[1]; q2 = row2[2];
        vP = ((const float2*)outputs)[idxP];
        lP = ((const float2*)labels)[idxP];
    }

    // ---- Prefetch B: 6 consecutive edges per thread (tid<1000 covers 6000),
    // endpoints via 3x int2 per row, then ea / V[j] for in-range edges
    // (independent of the hash) ----
    const bool act = tid < (EDGES_PER_B / EPT);
    int iv[EPT], jv[EPT];
    if (act) {
        const int* pi = ei + (size_t)b * EDGES_PER_B + tid * EPT;
        int2 e0 = *(const int2*)pi, e1 = *(const int2*)(pi + 2), e2 = *(const int2*)(pi + 4);
        const int* pj = pi + TOTAL_EDGES;
        int2 c0 = *(const int2*)pj, c1 = *(const int2*)(pj + 2), c2 = *(const int2*)(pj + 4);
        iv[0] = e0.x % N_BUSES; iv[1] = e0.y % N_BUSES; iv[2] = e1.x % N_BUSES;
        iv[3] = e1.y % N_BUSES; iv[4] = e2.x % N_BUSES; iv[5] = e2.y % N_BUSES;
        jv[0] = c0.x % N_BUSES; jv[1] = c0.y % N_BUSES; jv[2] = c1.x % N_BUSES;
        jv[3] = c1.y % N_BUSES; jv[4] = c2.x % N_BUSES; jv[5] = c2.y % N_BUSES;
    }
    float2 av[EPT], vv[EPT];
    bool inr[EPT];
#pragma unroll
    for (int k = 0; k < EPT; k++) {
        inr[k] = act && (iv[k] >= r0) && (iv[k] < r0 + BUS_PER);
        if (inr[k]) {
            av[k] = ((const float2*)ea)[b * EDGES_PER_B + tid * EPT + k];
            vv[k] = ((const float2*)outputs)[b * N_BUSES + jv[k]];
        }
    }

    // ---- Phase 0: zero LDS ----
    slots[tid] = 0ULL;
    slots[tid + TPB] = 0ULL;               // HSIZE == 2*TPB
    if (tid < 2 * BUS_PER) yv_sh[tid] = 0.0f;
    if (tid == 0) npend = 0;
    __syncthreads();

    // ---- Phase 1: single-pass dedup insert + compensated YV accumulation.
    // numpy fancy-assign: last write per (i,j) wins = max local edge id.
    // Duplicates share i => same block. Deposing a previous winner subtracts
    // its contribution (same key => same j => same V[j]).
#pragma unroll
    for (int k = 0; k < EPT; k++) {
        if (!inr[k]) continue;
        int e = tid * EPT + k;
        int i = iv[k], j = jv[k];
        int key = i * N_BUSES + j;
        ull tag = (ull)(unsigned)(key + 1) << 13;
        ull packed = tag | (unsigned)e;
        unsigned h = hash_key(key);
        int deposed = -1;
        bool we_add = false;
        while (true) {
            ull old = atomicCAS(&slots[h], 0ULL, packed);
            if (old == 0ULL) { we_add = true; break; }
            if ((old >> 13) == (ull)(unsigned)(key + 1)) {
                ull prev = atomicMax(&slots[h], packed);
                if (prev < packed) { we_add = true; deposed = (int)(prev & 0x1FFFULL); }
                break;
            }
            h = (h + 1) & HMASK;
        }
        if (we_add) {
            float2 a = av[k], v = vv[k];
            float addr = a.x * v.x - a.y * v.y;
            float addi = a.x * v.y + a.y * v.x;
            if (deposed >= 0) {   // rare (~5 per image): undo deposed winner
                float2 ap = ((const float2*)ea)[b * EDGES_PER_B + deposed];
                addr -= ap.x * v.x - ap.y * v.y;
                addi -= ap.x * v.y + ap.y * v.x;
            }
            int il = i - r0;
            atomicAdd(&yv_sh[2 * il],     addr);
            atomicAdd(&yv_sh[2 * il + 1], addi);
        }
    }
    __syncthreads();

    // ---- Phase 2: per-bus loss terms over our 250-bus range ----
    double t0 = 0.0, t1 = 0.0, t2 = 0.0, t3 = 0.0, t4 = 0.0;
    if (tid < BUS_PER) {
        int il = tid;
        float sre = q0.x, sim = q0.y, Vm = q1.x;
        float bt0 = q1.y, bt1 = q2.x, bt2 = q2.y;
        if ((sre == 0.0f && sim == 0.0f) || Vm == 0.0f) {
            // exact-zero fallback needs image means — defer (rare/never)
            int pp = atomicAdd(&npend, 1);
            if (pp < 64) pend[pp] = il;
        } else {
            float yvr = yv_sh[2 * il], yvi = yv_sh[2 * il + 1];
            float spr = vP.x * yvr + vP.y * yvi;   // Spred = V * conj(YV)
            float spi = vP.y * yvr - vP.x * yvi;
            float den = sre * sre + sim * sim;
            float ir = sre / den, ii = -sim / den;
            float sinv_norm = sqrtf(ir * ir + ii * ii);
            float cr = spr - sre, ci = spi - sim;
            t0 = (double)(sinv_norm * ((cr * cr - ci * ci) * bt0 + (cr * cr) * bt1));
            t1 = (double)(sinv_norm * (2.0f * cr * ci * bt0));
            float vminv = 1.0f / Vm;
            float vmag = sqrtf(vP.x * vP.x + vP.y * vP.y);
            t2 = (double)(fabsf(vmag * (bt1 + bt2) - Vm) * vminv);
            t3 = (double)(fabsf(vP.y * bt2) * vminv);
            float e0 = vP.x - lP.x, e1 = vP.y - lP.y;
            t4 = (double)(e0 * e0 + e1 * e1);
        }
    }
    for (int off = 32; off > 0; off >>= 1) {
        t0 += __shfl_down(t0, off, 64);
        t1 += __shfl_down(t1, off, 64);
        t2 += __shfl_down(t2, off, 64);
        t3 += __shfl_down(t3, off, 64);
        t4 += __shfl_down(t4, off, 64);
    }
    if (lane == 0) {
        red[0][wave] = t0; red[1][wave] = t1; red[2][wave] = t2;
        red[3][wave] = t3; red[4][wave] = t4;
    }
    __syncthreads();

    double a0 = 0, a1 = 0, a2 = 0, a3 = 0, a4 = 0;
    if (tid == 0) {
        for (int w = 0; w < TPB / 64; w++) {
            a0 += red[0][w]; a1 += red[1][w]; a2 += red[2][w];
            a3 += red[3][w]; a4 += red[4][w];
        }
    }

    // ---- Rare path: exact-zero S or Vm -> compute image means (bit-faithful)
    // and process pending buses serially. npend is uniform post-barrier.
    if (npend > 0) {
        double sre = 0.0, sim = 0.0, svm = 0.0;
        for (int i = tid; i < N_BUSES; i += TPB) {
            const float* row = x + (size_t)(b * N_BUSES + i) * 6;
            sre += (double)row[0];
            sim += (double)row[1];
            svm += (double)row[2];
        }
        for (int off = 32; off > 0; off >>= 1) {
            sre += __shfl_down(sre, off, 64);
            sim += __shfl_down(sim, off, 64);
            svm += __shfl_down(svm, off, 64);
        }
        if (lane == 0) { red2[0][wave] = sre; red2[1][wave] = sim; red2[2][wave] = svm; }
        __syncthreads();
        if (tid == 0) {
            double sa = 0, sb = 0, sc = 0;
            for (int w = 0; w < TPB / 64; w++) { sa += red2[0][w]; sb += red2[1][w]; sc += red2[2][w]; }
            bst[0] = (float)(sa / N_BUSES);
            bst[1] = (float)(sb / N_BUSES);
            bst[2] = (float)(sc / N_BUSES);
        }
        __syncthreads();
        if (tid == 0) {
            int np = npend < 64 ? npend : 64;
            for (int q = 0; q < np; q++) {
                int il = pend[q];
                int idx = b * N_BUSES + r0 + il;
                const float2* row2 = (const float2*)(x + (size_t)idx * 6);
                float2 w0 = row2[0], w1 = row2[1], w2 = row2[2];
                float sr = w0.x, si = w0.y, Vm = w1.x;
                float bt0 = w1.y, bt1 = w2.x, bt2 = w2.y;
                float2 v = ((const float2*)outputs)[idx];
                float yvr = yv_sh[2 * il], yvi = yv_sh[2 * il + 1];
                float spr = v.x * yvr + v.y * yvi;
                float spi = v.y * yvr - v.x * yvi;
                float ir, ii;
                if (sr != 0.0f || si != 0.0f) {
                    float den = sr * sr + si * si;
                    ir = sr / den; ii = -si / den;
                } else {
                    float mr = bst[0], mi = bst[1];
                    float den = mr * mr + mi * mi;
                    ir = mr / den; ii = -mi / den;
                }
                float sinv_norm = sqrtf(ir * ir + ii * ii);
                float cr = spr - sr, ci = spi - si;
                a0 += (double)(sinv_norm * ((cr * cr - ci * ci) * bt0 + (cr * cr) * bt1));
                a1 += (double)(sinv_norm * (2.0f * cr * ci * bt0));
                float vminv = (Vm != 0.0f) ? (1.0f / Vm) : (1.0f / bst[2]);
                float vmag = sqrtf(v.x * v.x + v.y * v.y);
                a2 += (double)(fabsf(vmag * (bt1 + bt2) - Vm) * vminv);
                a3 += (double)(fabsf(v.y * bt2) * vminv);
                float2 l = ((const float2*)labels)[idx];
                float e0 = v.x - l.x, e1 = v.y - l.y;
                a4 += (double)(e0 * e0 + e1 * e1);
            }
        }
    }

    // ---- Publish partials (device-scope atomics, coherence-point ops), then
    // grab a ticket; the 256th block performs the final reduction ----
    if (tid == 0) {
        atomicExch((ull*)&part[blk * 5 + 0], __double_as_longlong(a0));
        atomicExch((ull*)&part[blk * 5 + 1], __double_as_longlong(a1));
        atomicExch((ull*)&part[blk * 5 + 2], __double_as_longlong(a2));
        atomicExch((ull*)&part[blk * 5 + 3], __double_as_longlong(a3));
        atomicExch((ull*)&part[blk * 5 + 4], __double_as_longlong(a4));
        __threadfence();
        unsigned t = atomicAdd(ticket, 1u);
        amLast = (t == NBLOCKS - 1) ? 1 : 0;
    }
    __syncthreads();
    if (!amLast) return;

    // ---- Final reduction (one block): 256 partials, 5 doubles each ----
    double v0 = 0, v1 = 0, v2 = 0, v3 = 0, v4 = 0;
    if (tid < NBLOCKS) {
        v0 = atomicAdd(&part[tid * 5 + 0], 0.0);   // coherent cross-XCD read
        v1 = atomicAdd(&part[tid * 5 + 1], 0.0);
        v2 = atomicAdd(&part[tid * 5 + 2], 0.0);
        v3 = atomicAdd(&part[tid * 5 + 3], 0.0);
        v4 = atomicAdd(&part[tid * 5 + 4], 0.0);
    }
    for (int off = 32; off > 0; off >>= 1) {
        v0 += __shfl_down(v0, off, 64);
        v1 += __shfl_down(v1, off, 64);
        v2 += __shfl_down(v2, off, 64);
        v3 += __shfl_down(v3, off, 64);
        v4 += __shfl_down(v4, off, 64);
    }
    __syncthreads();   // red[] reuse
    if (lane == 0 && tid < NBLOCKS) {
        red[0][wave] = v0; red[1][wave] = v1; red[2][wave] = v2;
        red[3][wave] = v3; red[4][wave] = v4;
    }
    __syncthreads();
    if (tid == 0) {
        double s0 = 0, s1 = 0, s2 = 0, s3 = 0, s4 = 0;
        for (int w = 0; w < NBLOCKS / 64; w++) {
            s0 += red[0][w]; s1 += red[1][w]; s2 += red[2][w];
            s3 += red[3][w]; s4 += red[4][w];
        }
        double inv = 1.0 / (double)TOTAL_BUSES;
        double d1re = s0 * inv, d1im = s1 * inv;
        double d2 = s2 * inv, d3 = s3 * inv;
        double mse = s4 / (2.0 * (double)TOTAL_BUSES);
        double phre = d1re + d2 + d3, phim = d1im;
        double lre = mse + 0.1 * phre, lim = 0.1 * phim;
        if (out_size == 8) {
            out[0] = (float)lre;  out[1] = (float)lim;
            out[2] = (float)phre; out[3] = (float)phim;
            out[4] = (float)d1re; out[5] = (float)d1im;
            out[6] = (float)d2;   out[7] = (float)d3;
        } else {
            float vals[5] = {(float)lre, (float)phre, (float)d1re, (float)d2, (float)d3};
            int n = out_size < 5 ? out_size : 5;
            for (int k = 0; k < n; k++) out[k] = vals[k];
            for (int k = 5; k < out_size && k < 64; k++) out[k] = 0.0f;
        }
    }
}

extern "C" void kernel_launch(void* const* d_in, const int* in_sizes, int n_in,
                              void* d_out, int out_size, void* d_ws, size_t ws_size,
                              hipStream_t stream) {
    const float* x       = (const float*)d_in[0];
    const float* ea      = (const float*)d_in[1];
    const int*   ei      = (const int*)d_in[2];
    const float* outputs = (const float*)d_in[3];
    const float* labels  = (const float*)d_in[4];
    unsigned* ticket = (unsigned*)d_ws;
    double* part = (double*)((char*)d_ws + OFF_PART);   // NBLOCKS*5 doubles

    hipMemsetAsync(ticket, 0, sizeof(unsigned), stream);
    fused_split<<<NBLOCKS, TPB, 0, stream>>>(x, ea, ei, outputs, labels, part,
                                             ticket, (float*)d_out, out_size);
}

// Round 9
// 85.258 us; speedup vs baseline: 1.4378x; 1.0192x over previous
//
#include <hip/hip_runtime.h>

typedef unsigned long long ull;

// Problem constants (from reference)
#define N_BUSES     2000
#define BATCH       32
#define EDGES_PER_B 6000
#define TOTAL_BUSES (BATCH * N_BUSES)     // 64000
#define TOTAL_EDGES (BATCH * EDGES_PER_B) // 192000

#define SPLIT   8                         // blocks per image (bus-range partition)
#define BUS_PER (N_BUSES / SPLIT)         // 250 buses per block
#define TPB     1024
#define NBLOCKS (BATCH * SPLIT)           // 256 (fully co-resident: 16 waves/CU)
#define EPT     6                         // 6 consecutive edges per thread (tid < 1000)

// Per-block LDS hash: slot = ((key+1) << 13) | local_edge_id, 0 = empty.
// key = i*N_BUSES + j < 4e6 < 2^22; local edge id < 6000 < 2^13.
// ~750 keys/block in 2048 slots => load ~0.37.
#define HBITS 11
#define HSIZE (1 << HBITS)
#define HMASK (HSIZE - 1)

__device__ __forceinline__ unsigned hash_key(int key) {
    return ((unsigned)key * 2654435761u) >> (32 - HBITS);
}

__global__ __launch_bounds__(TPB)
void fused_split(const float* __restrict__ x, const float* __restrict__ ea,
                 const int* __restrict__ ei, const float* __restrict__ outputs,
                 const float* __restrict__ labels, double* __restrict__ part) {
    __shared__ ull slots[HSIZE];           // 16 KB
    __shared__ float yv_sh[2 * BUS_PER];   // 2 KB
    __shared__ double red[5][TPB / 64];
    __shared__ double red2[3][TPB / 64];
    __shared__ float bst[3];
    __shared__ int pend[64];
    __shared__ int npend;

    const int blk = blockIdx.x;
    const int b = blk / SPLIT;             // image
    const int p = blk % SPLIT;             // bus-range part
    const int r0 = p * BUS_PER;
    const int tid = threadIdx.x;
    const int wave = tid >> 6, lane = tid & 63;

    // ---- Prefetch A: phase-2 operands (independent; in flight through the
    // whole edge phase) ----
    float2 q0, q1, q2, vP, lP;
    const int idxP = b * N_BUSES + r0 + tid;   // valid when tid < BUS_PER
    if (tid < BUS_PER) {
        const float2* row2 = (const float2*)(x + (size_t)idxP * 6);
        q0 = row2[0]; q1 = row2[1]; q2 = row2[2];
        vP = ((const float2*)outputs)[idxP];
        lP = ((const float2*)labels)[idxP];
    }

    // ---- Prefetch B: 6 consecutive edges per thread (tid<1000 covers 6000).
    // Endpoints via 3x int2 per row; ea via 3x float4 (48B contiguous,
    // 16B-aligned) unconditionally — fewer VMEM ops, no divergence.
    // V[j] gathers only for in-range edges (independent of the hash). ----
    const bool act = tid < (EDGES_PER_B / EPT);
    int iv[EPT], jv[EPT];
    float2 av[EPT];
    if (act) {
        const int* pi = ei + (size_t)b * EDGES_PER_B + tid * EPT;
        int2 e0 = *(const int2*)pi, e1 = *(const int2*)(pi + 2), e2 = *(const int2*)(pi + 4);
        const int* pj = pi + TOTAL_EDGES;
        int2 c0 = *(const int2*)pj, c1 = *(const int2*)(pj + 2), c2 = *(const int2*)(pj + 4);
        const float4* pa = (const float4*)(ea + (size_t)(b * EDGES_PER_B + tid * EPT) * 2);
        float4 f0 = pa[0], f1 = pa[1], f2 = pa[2];
        iv[0] = e0.x % N_BUSES; iv[1] = e0.y % N_BUSES; iv[2] = e1.x % N_BUSES;
        iv[3] = e1.y % N_BUSES; iv[4] = e2.x % N_BUSES; iv[5] = e2.y % N_BUSES;
        jv[0] = c0.x % N_BUSES; jv[1] = c0.y % N_BUSES; jv[2] = c1.x % N_BUSES;
        jv[3] = c1.y % N_BUSES; jv[4] = c2.x % N_BUSES; jv[5] = c2.y % N_BUSES;
        av[0] = make_float2(f0.x, f0.y); av[1] = make_float2(f0.z, f0.w);
        av[2] = make_float2(f1.x, f1.y); av[3] = make_float2(f1.z, f1.w);
        av[4] = make_float2(f2.x, f2.y); av[5] = make_float2(f2.z, f2.w);
    }
    float2 vv[EPT];
    bool inr[EPT];
#pragma unroll
    for (int k = 0; k < EPT; k++) {
        inr[k] = act && (iv[k] >= r0) && (iv[k] < r0 + BUS_PER);
        if (inr[k]) vv[k] = ((const float2*)outputs)[b * N_BUSES + jv[k]];
    }

    // ---- Phase 0: zero LDS ----
    slots[tid] = 0ULL;
    slots[tid + TPB] = 0ULL;               // HSIZE == 2*TPB
    if (tid < 2 * BUS_PER) yv_sh[tid] = 0.0f;
    if (tid == 0) npend = 0;
    __syncthreads();

    // ---- Phase 1: single-pass dedup insert + compensated YV accumulation.
    // numpy fancy-assign: last write per (i,j) wins = max local edge id.
    // Duplicates share i => same block. Deposing a previous winner subtracts
    // its contribution (same key => same j => same V[j]).
#pragma unroll
    for (int k = 0; k < EPT; k++) {
        if (!inr[k]) continue;
        int e = tid * EPT + k;
        int i = iv[k], j = jv[k];
        int key = i * N_BUSES + j;
        ull tag = (ull)(unsigned)(key + 1) << 13;
        ull packed = tag | (unsigned)e;
        unsigned h = hash_key(key);
        int deposed = -1;
        bool we_add = false;
        while (true) {
            ull old = atomicCAS(&slots[h], 0ULL, packed);
            if (old == 0ULL) { we_add = true; break; }
            if ((old >> 13) == (ull)(unsigned)(key + 1)) {
                ull prev = atomicMax(&slots[h], packed);
                if (prev < packed) { we_add = true; deposed = (int)(prev & 0x1FFFULL); }
                break;
            }
            h = (h + 1) & HMASK;
        }
        if (we_add) {
            float2 a = av[k], v = vv[k];
            float addr = a.x * v.x - a.y * v.y;
            float addi = a.x * v.y + a.y * v.x;
            if (deposed >= 0) {   // rare (~5 per image): undo deposed winner
                float2 ap = ((const float2*)ea)[b * EDGES_PER_B + deposed];
                addr -= ap.x * v.x - ap.y * v.y;
                addi -= ap.x * v.y + ap.y * v.x;
            }
            int il = i - r0;
            atomicAdd(&yv_sh[2 * il],     addr);
            atomicAdd(&yv_sh[2 * il + 1], addi);
        }
    }
    __syncthreads();

    // ---- Phase 2: per-bus loss terms over our 250-bus range ----
    double t0 = 0.0, t1 = 0.0, t2 = 0.0, t3 = 0.0, t4 = 0.0;
    if (tid < BUS_PER) {
        int il = tid;
        float sre = q0.x, sim = q0.y, Vm = q1.x;
        float bt0 = q1.y, bt1 = q2.x, bt2 = q2.y;
        if ((sre == 0.0f && sim == 0.0f) || Vm == 0.0f) {
            // exact-zero fallback needs image means — defer (rare/never)
            int pp = atomicAdd(&npend, 1);
            if (pp < 64) pend[pp] = il;
        } else {
            float yvr = yv_sh[2 * il], yvi = yv_sh[2 * il + 1];
            float spr = vP.x * yvr + vP.y * yvi;   // Spred = V * conj(YV)
            float spi = vP.y * yvr - vP.x * yvi;
            float den = sre * sre + sim * sim;
            float ir = sre / den, ii = -sim / den;
            float sinv_norm = sqrtf(ir * ir + ii * ii);
            float cr = spr - sre, ci = spi - sim;
            t0 = (double)(sinv_norm * ((cr * cr - ci * ci) * bt0 + (cr * cr) * bt1));
            t1 = (double)(sinv_norm * (2.0f * cr * ci * bt0));
            float vminv = 1.0f / Vm;
            float vmag = sqrtf(vP.x * vP.x + vP.y * vP.y);
            t2 = (double)(fabsf(vmag * (bt1 + bt2) - Vm) * vminv);
            t3 = (double)(fabsf(vP.y * bt2) * vminv);
            float e0 = vP.x - lP.x, e1 = vP.y - lP.y;
            t4 = (double)(e0 * e0 + e1 * e1);
        }
    }
    for (int off = 32; off > 0; off >>= 1) {
        t0 += __shfl_down(t0, off, 64);
        t1 += __shfl_down(t1, off, 64);
        t2 += __shfl_down(t2, off, 64);
        t3 += __shfl_down(t3, off, 64);
        t4 += __shfl_down(t4, off, 64);
    }
    if (lane == 0) {
        red[0][wave] = t0; red[1][wave] = t1; red[2][wave] = t2;
        red[3][wave] = t3; red[4][wave] = t4;
    }
    __syncthreads();

    double a0 = 0, a1 = 0, a2 = 0, a3 = 0, a4 = 0;
    if (tid == 0) {
        for (int w = 0; w < TPB / 64; w++) {
            a0 += red[0][w]; a1 += red[1][w]; a2 += red[2][w];
            a3 += red[3][w]; a4 += red[4][w];
        }
    }

    // ---- Rare path: exact-zero S or Vm -> compute image means (bit-faithful)
    // and process pending buses serially. npend is uniform post-barrier.
    if (npend > 0) {
        double sre = 0.0, sim = 0.0, svm = 0.0;
        for (int i = tid; i < N_BUSES; i += TPB) {
            const float* row = x + (size_t)(b * N_BUSES + i) * 6;
            sre += (double)row[0];
            sim += (double)row[1];
            svm += (double)row[2];
        }
        for (int off = 32; off > 0; off >>= 1) {
            sre += __shfl_down(sre, off, 64);
            sim += __shfl_down(sim, off, 64);
            svm += __shfl_down(svm, off, 64);
        }
        if (lane == 0) { red2[0][wave] = sre; red2[1][wave] = sim; red2[2][wave] = svm; }
        __syncthreads();
        if (tid == 0) {
            double sa = 0, sb = 0, sc = 0;
            for (int w = 0; w < TPB / 64; w++) { sa += red2[0][w]; sb += red2[1][w]; sc += red2[2][w]; }
            bst[0] = (float)(sa / N_BUSES);
            bst[1] = (float)(sb / N_BUSES);
            bst[2] = (float)(sc / N_BUSES);
        }
        __syncthreads();
        if (tid == 0) {
            int np = npend < 64 ? npend : 64;
            for (int q = 0; q < np; q++) {
                int il = pend[q];
                int idx = b * N_BUSES + r0 + il;
                const float2* row2 = (const float2*)(x + (size_t)idx * 6);
                float2 w0 = row2[0], w1 = row2[1], w2 = row2[2];
                float sr = w0.x, si = w0.y, Vm = w1.x;
                float bt0 = w1.y, bt1 = w2.x, bt2 = w2.y;
                float2 v = ((const float2*)outputs)[idx];
                float yvr = yv_sh[2 * il], yvi = yv_sh[2 * il + 1];
                float spr = v.x * yvr + v.y * yvi;
                float spi = v.y * yvr - v.x * yvi;
                float ir, ii;
                if (sr != 0.0f || si != 0.0f) {
                    float den = sr * sr + si * si;
                    ir = sr / den; ii = -si / den;
                } else {
                    float mr = bst[0], mi = bst[1];
                    float den = mr * mr + mi * mi;
                    ir = mr / den; ii = -mi / den;
                }
                float sinv_norm = sqrtf(ir * ir + ii * ii);
                float cr = spr - sr, ci = spi - si;
                a0 += (double)(sinv_norm * ((cr * cr - ci * ci) * bt0 + (cr * cr) * bt1));
                a1 += (double)(sinv_norm * (2.0f * cr * ci * bt0));
                float vminv = (Vm != 0.0f) ? (1.0f / Vm) : (1.0f / bst[2]);
                float vmag = sqrtf(v.x * v.x + v.y * v.y);
                a2 += (double)(fabsf(vmag * (bt1 + bt2) - Vm) * vminv);
                a3 += (double)(fabsf(v.y * bt2) * vminv);
                float2 l = ((const float2*)labels)[idx];
                float e0 = v.x - l.x, e1 = v.y - l.y;
                a4 += (double)(e0 * e0 + e1 * e1);
            }
        }
    }

    if (tid == 0) {
        part[blk * 5 + 0] = a0; part[blk * 5 + 1] = a1; part[blk * 5 + 2] = a2;
        part[blk * 5 + 3] = a3; part[blk * 5 + 4] = a4;
    }
}

__global__ __launch_bounds__(256)
void finalize(const double* __restrict__ part, float* __restrict__ out, int out_size) {
    int tid = threadIdx.x;               // 256 threads, one per block partial
    int wave = tid >> 6, lane = tid & 63;
    double v0 = part[tid * 5 + 0], v1 = part[tid * 5 + 1], v2 = part[tid * 5 + 2];
    double v3 = part[tid * 5 + 3], v4 = part[tid * 5 + 4];
    for (int off = 32; off > 0; off >>= 1) {
        v0 += __shfl_down(v0, off, 64);
        v1 += __shfl_down(v1, off, 64);
        v2 += __shfl_down(v2, off, 64);
        v3 += __shfl_down(v3, off, 64);
        v4 += __shfl_down(v4, off, 64);
    }
    __shared__ double sh[5][4];
    if (lane == 0) {
        sh[0][wave] = v0; sh[1][wave] = v1; sh[2][wave] = v2;
        sh[3][wave] = v3; sh[4][wave] = v4;
    }
    __syncthreads();
    if (tid == 0) {
        double a0 = 0, a1 = 0, a2 = 0, a3 = 0, a4 = 0;
        for (int w = 0; w < 4; w++) {
            a0 += sh[0][w]; a1 += sh[1][w]; a2 += sh[2][w];
            a3 += sh[3][w]; a4 += sh[4][w];
        }
        double inv = 1.0 / (double)TOTAL_BUSES;
        double d1re = a0 * inv, d1im = a1 * inv;
        double d2 = a2 * inv, d3 = a3 * inv;
        double mse = a4 / (2.0 * (double)TOTAL_BUSES);
        double phre = d1re + d2 + d3, phim = d1im;
        double lre = mse + 0.1 * phre, lim = 0.1 * phim;
        if (out_size == 8) {
            out[0] = (float)lre;  out[1] = (float)lim;
            out[2] = (float)phre; out[3] = (float)phim;
            out[4] = (float)d1re; out[5] = (float)d1im;
            out[6] = (float)d2;   out[7] = (float)d3;
        } else {
            float vals[5] = {(float)lre, (float)phre, (float)d1re, (float)d2, (float)d3};
            int n = out_size < 5 ? out_size : 5;
            for (int k = 0; k < n; k++) out[k] = vals[k];
            for (int k = 5; k < out_size && k < 64; k++) out[k] = 0.0f;
        }
    }
}

extern "C" void kernel_launch(void* const* d_in, const int* in_sizes, int n_in,
                              void* d_out, int out_size, void* d_ws, size_t ws_size,
                              hipStream_t stream) {
    const float* x       = (const float*)d_in[0];
    const float* ea      = (const float*)d_in[1];
    const int*   ei      = (const int*)d_in[2];
    const float* outputs = (const float*)d_in[3];
    const float* labels  = (const float*)d_in[4];
    double* part = (double*)d_ws;   // NBLOCKS * 5 doubles = 10 KB

    fused_split<<<NBLOCKS, TPB, 0, stream>>>(x, ea, ei, outputs, labels, part);
    finalize<<<1, 256, 0, stream>>>(part, (float*)d_out, out_size);
}